// Round 3
// baseline (925.849 us; speedup 1.0000x reference)
//
#include <hip/hip_runtime.h>
#include <cstdint>
#include <cstddef>

#define N_TOK 8192
#define DIM   1024
#define NEXP  8
#define HID   2816
#define CAP   1280   // int(1.25 * 8192 / 8)

typedef __bf16 bf16x8 __attribute__((ext_vector_type(8)));
typedef float  floatx4 __attribute__((ext_vector_type(4)));
typedef unsigned short u16x8 __attribute__((ext_vector_type(8)));

__device__ __forceinline__ unsigned short f2bf(float f) {
  return __builtin_bit_cast(unsigned short, (__bf16)f);
}

// async global->LDS, 16B per lane. LDS dest must be wave-uniform base + lane*16.
__device__ __forceinline__ void async16(void* lds, const void* g) {
  __builtin_amdgcn_global_load_lds(
      (const __attribute__((address_space(1))) void*)g,
      (__attribute__((address_space(3))) void*)lds, 16, 0, 0);
}

__device__ __forceinline__ void fence_barrier() {
  asm volatile("" ::: "memory");
  __builtin_amdgcn_s_barrier();
  asm volatile("" ::: "memory");
}

__device__ __forceinline__ floatx4 mfma16(bf16x8 a, bf16x8 b, floatx4 c) {
  return __builtin_amdgcn_mfma_f32_16x16x32_bf16(a, b, c, 0, 0, 0);
}

// ---------------------------------------------------------------------------
// Routing: FCFS position of each token in its expert queue. One block, 256 thr.
// Parallel Hillis-Steele scan over the 256 chunk-histograms (all 8 experts at
// once); static-indexed local counters (no scratch).
// ---------------------------------------------------------------------------
__global__ void route_kernel(const int* __restrict__ idx, int idx_stride,
                             int* __restrict__ slot,
                             int* __restrict__ slot_token,
                             int* __restrict__ counts) {
  __shared__ int hist[256][NEXP];
  const int t = threadIdx.x;
  int loc[NEXP];
#pragma unroll
  for (int e = 0; e < NEXP; e++) loc[e] = 0;
  const int base = t * 32;
  for (int i = 0; i < 32; i++) {
    const int e = idx[(base + i) * idx_stride];
#pragma unroll
    for (int k = 0; k < NEXP; k++) loc[k] += (e == k) ? 1 : 0;
  }
  int v[NEXP];
#pragma unroll
  for (int e = 0; e < NEXP; e++) { v[e] = loc[e]; hist[t][e] = loc[e]; }
  __syncthreads();
  // inclusive scan across the 256 chunks, 8 experts in parallel
  for (int d = 1; d < 256; d <<= 1) {
    int nb[NEXP];
    const bool has = (t >= d);
    if (has) {
#pragma unroll
      for (int e = 0; e < NEXP; e++) nb[e] = hist[t - d][e];
    }
    __syncthreads();
    if (has) {
#pragma unroll
      for (int e = 0; e < NEXP; e++) { v[e] += nb[e]; hist[t][e] = v[e]; }
    }
    __syncthreads();
  }
  if (t < NEXP) {
    const int tot = hist[255][t];
    counts[t] = tot < CAP ? tot : CAP;
  }
  int b2[NEXP];
#pragma unroll
  for (int e = 0; e < NEXP; e++) b2[e] = v[e] - loc[e];  // exclusive base
  for (int i = 0; i < 32; i++) {
    const int n = base + i;
    const int e = idx[n * idx_stride];
    int p = 0;
#pragma unroll
    for (int k = 0; k < NEXP; k++) {
      if (e == k) { p = b2[k]; b2[k] = p + 1; }
    }
    if (p < CAP) {
      const int s = e * CAP + p;
      slot[n] = s;
      slot_token[s] = n;
    } else {
      slot[n] = -1;  // dropped -> passthrough
    }
  }
}

// ---------------------------------------------------------------------------
// Dispatch: kept tokens -> bf16 xe[slot]; dropped tokens -> y = x (fp32).
// ---------------------------------------------------------------------------
__global__ void dispatch_kernel(const float* __restrict__ x,
                                const int* __restrict__ slot,
                                unsigned short* __restrict__ xe,
                                float* __restrict__ y) {
  const int n = blockIdx.x;
  const int t = threadIdx.x;
  const int s = slot[n];
  const float4 v = ((const float4*)(x + (size_t)n * DIM))[t];
  if (s >= 0) {
    ushort4 b;
    b.x = f2bf(v.x); b.y = f2bf(v.y); b.z = f2bf(v.z); b.w = f2bf(v.w);
    ((ushort4*)(xe + (size_t)s * DIM))[t] = b;
  } else {
    ((float4*)(y + (size_t)n * DIM))[t] = v;
  }
}

// ---------------------------------------------------------------------------
// Transpose + fp32->bf16: in [E][R][C] fp32 -> out [E][C][R] bf16.
// ---------------------------------------------------------------------------
__global__ __launch_bounds__(256)
void transpose_cvt(const float* __restrict__ in,
                   unsigned short* __restrict__ out,
                   const int R, const int C) {
  __shared__ float tile[64][65];
  const int e = blockIdx.z;
  const float* ib = in + (size_t)e * R * C;
  unsigned short* ob = out + (size_t)e * R * C;
  const int t = threadIdx.x;
  const int c0 = blockIdx.x * 64, r0 = blockIdx.y * 64;
  const int lr = t >> 4;          // 0..15
  const int lc = (t & 15) * 4;    // 0..60
#pragma unroll
  for (int i = 0; i < 4; i++) {
    const float4 v = *(const float4*)(ib + (size_t)(r0 + lr + i * 16) * C + c0 + lc);
    tile[lr + i * 16][lc + 0] = v.x;
    tile[lr + i * 16][lc + 1] = v.y;
    tile[lr + i * 16][lc + 2] = v.z;
    tile[lr + i * 16][lc + 3] = v.w;
  }
  __syncthreads();
  const int oc = t >> 2;          // out row (original col) 0..63
  const int sub = t & 3;
#pragma unroll
  for (int half = 0; half < 2; half++) {
    const int rch = sub + half * 4;  // chunk of 8 original rows
    u16x8 o;
#pragma unroll
    for (int j = 0; j < 8; j++) o[j] = f2bf(tile[rch * 8 + j][oc]);
    *(u16x8*)(ob + (size_t)(c0 + oc) * R + r0 + rch * 8) = o;
  }
}

// ---------------------------------------------------------------------------
// Fused gate+up grouped GEMM. Tile 256M x 128N (x2 matrices), BK=64, 8 waves,
// read-once fragments, 2 phases/K-tile. B (weights, zero-reuse HBM stream) is
// REG-STAGED: global->VGPR at p0(T) for tile T+2, ds_write at p1(T) for T+1.
// This decouples B's in-flight window from the A gl_lds vmcnt FIFO (waiting on
// A no longer force-drains B). A stays on global_load_lds with counted waits:
// steady p0 tail vmcnt(6) [completes B(T+1),A1(T)], p1 tail vmcnt(8)
// [completes A0(T+1) only]. LDS 128K: 2 buf x {A0|A1|Bg|Bu} 16K each, chunk
// swizzle LDS(r,c)=global(r, c^(r&7)) (read side identical to prior version).
// ---------------------------------------------------------------------------
__global__ __launch_bounds__(512, 2)
void gateup_gemm3(const unsigned short* __restrict__ A,
                  const unsigned short* __restrict__ Bg,
                  const unsigned short* __restrict__ Bu,
                  const int* __restrict__ counts,
                  unsigned short* __restrict__ hact) {
  extern __shared__ __align__(16) char smem[];
  // grid 880 = 8 xcd * (22 cgl * 5 m)
  const int bid = blockIdx.x;
  const int xcd = bid & 7;
  const int slotb = bid >> 3;      // 0..109
  const int m = slotb % 5;
  const int cgl = slotb / 5;       // 0..21
  const int cg = xcd + 8 * cgl;    // 0..175
  const int n = cg % 22;
  const int e = cg / 22;

  const int cnt = counts[e];
  const int m0 = m * 256;
  if (m0 >= cnt) return;
  const int n0 = n * 128;

  const int t = threadIdx.x;
  const int lane = t & 63;
  const int w = t >> 6;
  const int wr = w >> 2;     // 0..1
  const int wc = w & 3;      // 0..3
  const int li = lane & 15;
  const int q = lane >> 4;

  const int sr8 = t >> 3;
  const int cLog = (t & 7) ^ (sr8 & 7);
  const unsigned short* aB  = A  + ((size_t)e * CAP + m0 + sr8) * DIM + cLog * 8;
  const unsigned short* bgB = Bg + ((size_t)e * HID + n0 + sr8) * DIM + cLog * 8;
  const unsigned short* buB = Bu + ((size_t)e * HID + n0 + sr8) * DIM + cLog * 8;

  auto stageU = [&](int bb, int uoff, const unsigned short* s0, const unsigned short* s1) {
    async16(smem + bb * 65536 + uoff + t * 16, s0);
    async16(smem + bb * 65536 + uoff + 8192 + t * 16, s1);
  };

  const int rowA = (wr * 64 + li) * 128;
  const int rowB = (wc * 32 + li) * 128;
  const int c0 = (q ^ (li & 7)) * 16;

  floatx4 accg[8][2] = {};
  floatx4 accu[8][2] = {};

  constexpr int NT = DIM / 64;  // 16 K-tiles

  uint4 rg0[4], rg1[4];

  // ---- prologue ----
  // reg loads B(0), B(1); gl_lds A0(0),A1(0)->b0, A0(1)->b1.
  {
    rg0[0] = *(const uint4*)(bgB);
    rg0[1] = *(const uint4*)(bgB + (size_t)64 * DIM);
    rg0[2] = *(const uint4*)(buB);
    rg0[3] = *(const uint4*)(buB + (size_t)64 * DIM);
    rg1[0] = *(const uint4*)(bgB + 64);
    rg1[1] = *(const uint4*)(bgB + (size_t)64 * DIM + 64);
    rg1[2] = *(const uint4*)(buB + 64);
    rg1[3] = *(const uint4*)(buB + (size_t)64 * DIM + 64);
    __builtin_amdgcn_sched_barrier(0);
    stageU(0, 0,     aB,                     aB + (size_t)64 * DIM);
    stageU(0, 16384, aB + (size_t)128 * DIM, aB + (size_t)192 * DIM);
    stageU(1, 0,     aB + 64,                aB + (size_t)64 * DIM + 64);
    asm volatile("s_waitcnt vmcnt(10)" ::: "memory");  // B(0) regs ready
    *(uint4*)(smem + 32768 + t * 16)        = rg0[0];
    *(uint4*)(smem + 32768 + 8192 + t * 16) = rg0[1];
    *(uint4*)(smem + 49152 + t * 16)        = rg0[2];
    *(uint4*)(smem + 49152 + 8192 + t * 16) = rg0[3];
    asm volatile("s_waitcnt vmcnt(4)" ::: "memory");   // A0(0) ready (forces B(1))
    asm volatile("s_waitcnt lgkmcnt(0)" ::: "memory");
    fence_barrier();
  }

  // ---- main loop body (manual unroll-2 for static reg-set roles) ----
  auto body = [&](int T, int b, uint4 (&rgOld)[4], uint4 (&rgNew)[4]) {
    const int bn = b ^ 1;
    char* sb = smem + b * 65536;
    bf16x8 bgf[2][2], buf2[2][2];
    // ---- phase 0: A-half 0, read Bg/Bu once and cache ----
    {
      bf16x8 af[4][2];
#pragma unroll
      for (int mi = 0; mi < 4; mi++) {
        af[mi][0] = *(const bf16x8*)(sb + rowA + mi * 2048 + c0);
        af[mi][1] = *(const bf16x8*)(sb + rowA + mi * 2048 + (c0 ^ 64));
      }
#pragma unroll
      for (int ni = 0; ni < 2; ni++) {
        bgf[ni][0]  = *(const bf16x8*)(sb + 32768 + rowB + ni * 2048 + c0);
        bgf[ni][1]  = *(const bf16x8*)(sb + 32768 + rowB + ni * 2048 + (c0 ^ 64));
        buf2[ni][0] = *(const bf16x8*)(sb + 49152 + rowB + ni * 2048 + c0);
        buf2[ni][1] = *(const bf16x8*)(sb + 49152 + rowB + ni * 2048 + (c0 ^ 64));
      }
      if (T + 2 < NT) {  // issue B(T+2) -> regs
        rgNew[0] = *(const uint4*)(bgB + (T + 2) * 64);
        rgNew[1] = *(const uint4*)(bgB + (size_t)64 * DIM + (T + 2) * 64);
        rgNew[2] = *(const uint4*)(buB + (T + 2) * 64);
        rgNew[3] = *(const uint4*)(buB + (size_t)64 * DIM + (T + 2) * 64);
      }
      __builtin_amdgcn_sched_barrier(0);
      fence_barrier();
      asm volatile("s_waitcnt lgkmcnt(0)" ::: "memory");
      __builtin_amdgcn_sched_barrier(0);
      __builtin_amdgcn_s_setprio(1);
#pragma unroll
      for (int mi = 0; mi < 4; mi++)
#pragma unroll
        for (int ni = 0; ni < 2; ni++) {
          accg[mi][ni] = mfma16(af[mi][0], bgf[ni][0], accg[mi][ni]);
          accg[mi][ni] = mfma16(af[mi][1], bgf[ni][1], accg[mi][ni]);
          accu[mi][ni] = mfma16(af[mi][0], buf2[ni][0], accu[mi][ni]);
          accu[mi][ni] = mfma16(af[mi][1], buf2[ni][1], accu[mi][ni]);
        }
      __builtin_amdgcn_s_setprio(0);
      if (T + 2 < NT)      asm volatile("s_waitcnt vmcnt(6)" ::: "memory");
      else if (T + 1 < NT) asm volatile("s_waitcnt vmcnt(2)" ::: "memory");
      else                 asm volatile("s_waitcnt vmcnt(0)" ::: "memory");
      fence_barrier();
    }
    // ---- phase 1: A-half 1 (B frags from registers); write B(T+1) to LDS ----
    {
      bf16x8 af[4][2];
#pragma unroll
      for (int mi = 0; mi < 4; mi++) {
        af[mi][0] = *(const bf16x8*)(sb + 16384 + rowA + mi * 2048 + c0);
        af[mi][1] = *(const bf16x8*)(sb + 16384 + rowA + mi * 2048 + (c0 ^ 64));
      }
      if (T + 1 < NT) {  // ds_write B(T+1) -> bn (compiler waits rgOld's vmcnt)
        char* db = smem + bn * 65536;
        *(uint4*)(db + 32768 + t * 16)        = rgOld[0];
        *(uint4*)(db + 32768 + 8192 + t * 16) = rgOld[1];
        *(uint4*)(db + 49152 + t * 16)        = rgOld[2];
        *(uint4*)(db + 49152 + 8192 + t * 16) = rgOld[3];
      }
      if (T + 1 < NT)
        stageU(bn, 16384, aB + (size_t)128 * DIM + (T + 1) * 64,
                          aB + (size_t)192 * DIM + (T + 1) * 64);
      if (T + 2 < NT)
        stageU(b, 0, aB + (T + 2) * 64, aB + (size_t)64 * DIM + (T + 2) * 64);
      __builtin_amdgcn_sched_barrier(0);
      fence_barrier();
      asm volatile("s_waitcnt lgkmcnt(0)" ::: "memory");
      __builtin_amdgcn_sched_barrier(0);
      __builtin_amdgcn_s_setprio(1);
#pragma unroll
      for (int mi = 0; mi < 4; mi++)
#pragma unroll
        for (int ni = 0; ni < 2; ni++) {
          accg[4 + mi][ni] = mfma16(af[mi][0], bgf[ni][0], accg[4 + mi][ni]);
          accg[4 + mi][ni] = mfma16(af[mi][1], bgf[ni][1], accg[4 + mi][ni]);
          accu[4 + mi][ni] = mfma16(af[mi][0], buf2[ni][0], accu[4 + mi][ni]);
          accu[4 + mi][ni] = mfma16(af[mi][1], buf2[ni][1], accu[4 + mi][ni]);
        }
      __builtin_amdgcn_s_setprio(0);
      if (T + 2 < NT)      asm volatile("s_waitcnt vmcnt(8)" ::: "memory");
      else if (T + 1 < NT) asm volatile("s_waitcnt vmcnt(2)" ::: "memory");
      fence_barrier();
    }
  };

  for (int T = 0; T < NT; T += 2) {
    body(T,     0, rg1, rg0);
    body(T + 1, 1, rg0, rg1);
  }

  // epilogue: hact = silu(g)*u. C/D: col = lane&15, row = (lane>>4)*4 + reg.
  unsigned short* ob = hact + (size_t)e * CAP * HID;
#pragma unroll
  for (int mh = 0; mh < 2; mh++)
#pragma unroll
    for (int mi = 0; mi < 4; mi++)
#pragma unroll
      for (int r = 0; r < 4; r++) {
        const int row = m0 + mh * 128 + wr * 64 + mi * 16 + q * 4 + r;
        const size_t rb = (size_t)row * HID;
#pragma unroll
        for (int ni = 0; ni < 2; ni++) {
          const int col = n0 + wc * 32 + ni * 16 + li;
          const float g = accg[mh * 4 + mi][ni][r];
          const float u = accu[mh * 4 + mi][ni][r];
          ob[rb + col] = f2bf(g / (1.0f + __expf(-g)) * u);
        }
      }
}

// ---------------------------------------------------------------------------
// Down GEMM + fused gather/scale. Tile 128x128, BK=64, 4 waves, LDS 64 KiB
// (2 buf x {A 16K | B 16K}) -> 2 blocks/CU. B (Wd^T weights) reg-staged with
// 2-iter lead: load B(T+2)->regs pre-barrier, ds_write B(T+1) pre-barrier,
// gl_lds A(T+2) post-MFMA. Steady tail vmcnt(8) completes A(T+1) only.
// ---------------------------------------------------------------------------
__global__ __launch_bounds__(256, 2)
void down_gemm3(const unsigned short* __restrict__ A,
                const unsigned short* __restrict__ Bt,
                const int* __restrict__ counts,
                const int* __restrict__ slot_token,
                const float* __restrict__ scores,
                float* __restrict__ y) {
  extern __shared__ __align__(16) char smem[];
  // grid 640 = 8 xcd * (8 cgl * 10 m)
  const int bid = blockIdx.x;
  const int xcd = bid & 7;
  const int slotb = bid >> 3;      // 0..79
  const int m = slotb % 10;
  const int cgl = slotb / 10;      // 0..7
  const int cg = xcd + 8 * cgl;    // 0..63
  const int n = cg % 8;
  const int e = cg / 8;

  const int cnt = counts[e];
  const int m0 = m * 128;
  if (m0 >= cnt) return;
  const int n0 = n * 128;

  const int t = threadIdx.x;
  const int lane = t & 63;
  const int w = t >> 6;
  const int wr = w >> 1;     // 0..1
  const int wc = w & 1;      // 0..1
  const int li = lane & 15;
  const int q = lane >> 4;

  const int sr8 = t >> 3;    // 0..31
  const int cLog = (t & 7) ^ (sr8 & 7);
  const unsigned short* aB = A  + ((size_t)e * CAP + m0 + sr8) * HID + cLog * 8;
  const unsigned short* bB = Bt + ((size_t)e * DIM + n0 + sr8) * HID + cLog * 8;

  auto stageA = [&](int bb, int koff) {
#pragma unroll
    for (int j = 0; j < 4; j++)
      async16(smem + bb * 32768 + j * 4096 + t * 16, aB + (size_t)j * 32 * HID + koff);
  };

  const int rowA = (wr * 64 + li) * 128;
  const int rowB = (wc * 64 + li) * 128;
  const int c0 = (q ^ (li & 7)) * 16;

  floatx4 acc[4][4] = {};

  constexpr int NT = HID / 64;  // 44 K-tiles

  uint4 rg0[4], rg1[4];

  // ---- prologue: B(0),B(1) regs; A(0)->b0, A(1)->b1 gl_lds ----
  {
#pragma unroll
    for (int j = 0; j < 4; j++)
      rg0[j] = *(const uint4*)(bB + (size_t)j * 32 * HID);
#pragma unroll
    for (int j = 0; j < 4; j++)
      rg1[j] = *(const uint4*)(bB + (size_t)j * 32 * HID + 64);
    __builtin_amdgcn_sched_barrier(0);
    stageA(0, 0);
    stageA(1, 64);
    asm volatile("s_waitcnt vmcnt(12)" ::: "memory");  // B(0) regs ready
#pragma unroll
    for (int j = 0; j < 4; j++)
      *(uint4*)(smem + 16384 + j * 4096 + t * 16) = rg0[j];
    asm volatile("s_waitcnt vmcnt(4)" ::: "memory");   // A(0) ready (forces B(1))
    asm volatile("s_waitcnt lgkmcnt(0)" ::: "memory");
    fence_barrier();
  }

  auto body = [&](int T, int b, uint4 (&rgOld)[4], uint4 (&rgNew)[4]) {
    const int bn = b ^ 1;
    char* sb = smem + b * 32768;
    bf16x8 af[4][2], bfr[4][2];
#pragma unroll
    for (int mi = 0; mi < 4; mi++) {
      af[mi][0] = *(const bf16x8*)(sb + rowA + mi * 2048 + c0);
      af[mi][1] = *(const bf16x8*)(sb + rowA + mi * 2048 + (c0 ^ 64));
    }
#pragma unroll
    for (int ni = 0; ni < 4; ni++) {
      bfr[ni][0] = *(const bf16x8*)(sb + 16384 + rowB + ni * 2048 + c0);
      bfr[ni][1] = *(const bf16x8*)(sb + 16384 + rowB + ni * 2048 + (c0 ^ 64));
    }
    if (T + 2 < NT) {  // issue B(T+2) -> regs
#pragma unroll
      for (int j = 0; j < 4; j++)
        rgNew[j] = *(const uint4*)(bB + (size_t)j * 32 * HID + (T + 2) * 64);
    }
    if (T + 1 < NT) {  // ds_write B(T+1) -> bn (compiler waits rgOld's vmcnt)
      char* db = smem + bn * 32768;
#pragma unroll
      for (int j = 0; j < 4; j++)
        *(uint4*)(db + 16384 + j * 4096 + t * 16) = rgOld[j];
    }
    __builtin_amdgcn_sched_barrier(0);
    fence_barrier();
    asm volatile("s_waitcnt lgkmcnt(0)" ::: "memory");
    __builtin_amdgcn_sched_barrier(0);
    __builtin_amdgcn_s_setprio(1);
#pragma unroll
    for (int mi = 0; mi < 4; mi++)
#pragma unroll
      for (int ni = 0; ni < 4; ni++) {
        acc[mi][ni] = mfma16(af[mi][0], bfr[ni][0], acc[mi][ni]);
        acc[mi][ni] = mfma16(af[mi][1], bfr[ni][1], acc[mi][ni]);
      }
    __builtin_amdgcn_s_setprio(0);
    if (T + 2 < NT) stageA(b, (T + 2) * 64);
    if (T + 2 < NT)      asm volatile("s_waitcnt vmcnt(8)" ::: "memory");
    else if (T + 1 < NT) asm volatile("s_waitcnt vmcnt(0)" ::: "memory");
    fence_barrier();
  };

  for (int T = 0; T < NT; T += 2) {
    body(T,     0, rg1, rg0);
    body(T + 1, 1, rg0, rg1);
  }

  // epilogue: y[tok] = acc * score (row < cnt only)
#pragma unroll
  for (int mi = 0; mi < 4; mi++)
#pragma unroll
    for (int r = 0; r < 4; r++) {
      const int row = m0 + wr * 64 + mi * 16 + q * 4 + r;
      if (row < cnt) {
        const int tok = slot_token[e * CAP + row];
        const float s = scores[tok];
        float* yr = y + (size_t)tok * DIM;
#pragma unroll
        for (int ni = 0; ni < 4; ni++) {
          const int col = n0 + wc * 64 + ni * 16 + li;
          yr[col] = acc[mi][ni][r] * s;
        }
      }
    }
}

extern "C" void kernel_launch(void* const* d_in, const int* in_sizes, int n_in,
                              void* d_out, int out_size, void* d_ws, size_t ws_size,
                              hipStream_t stream) {
  const float* x      = (const float*)d_in[0];
  const int*   idx    = (const int*)d_in[1];
  const float* scores = (const float*)d_in[2];
  const float* Wg     = (const float*)d_in[3];
  const float* Wu     = (const float*)d_in[4];
  const float* Wd     = (const float*)d_in[5];
  float* y = (float*)d_out;

  const int idx_stride = (in_sizes[1] == 2 * N_TOK) ? 2 : 1;

  char* ws = (char*)d_ws;
  size_t off = 0;
  auto alloc = [&](size_t b) -> char* {
    char* p = ws + off;
    off += (b + 255) & ~(size_t)255;
    return p;
  };
  int* counts            = (int*)alloc(NEXP * 4);
  int* slot              = (int*)alloc((size_t)N_TOK * 4);
  int* slot_token        = (int*)alloc((size_t)NEXP * CAP * 4);
  unsigned short* xe     = (unsigned short*)alloc((size_t)NEXP * CAP * DIM * 2);
  unsigned short* hact   = (unsigned short*)alloc((size_t)NEXP * CAP * HID * 2);
  unsigned short* wg_t   = (unsigned short*)alloc((size_t)NEXP * DIM * HID * 2);
  unsigned short* wu_t   = (unsigned short*)alloc((size_t)NEXP * DIM * HID * 2);
  unsigned short* wd_t   = (unsigned short*)alloc((size_t)NEXP * DIM * HID * 2);
  (void)ws_size; (void)n_in; (void)out_size;

  static bool s_attr_done = false;
  if (!s_attr_done) {
    hipFuncSetAttribute((const void*)gateup_gemm3,
                        hipFuncAttributeMaxDynamicSharedMemorySize, 131072);
    hipFuncSetAttribute((const void*)down_gemm3,
                        hipFuncAttributeMaxDynamicSharedMemorySize, 65536);
    s_attr_done = true;
  }

  route_kernel<<<1, 256, 0, stream>>>(idx, idx_stride, slot, slot_token, counts);
  dispatch_kernel<<<N_TOK, 256, 0, stream>>>(x, slot, xe, y);

  // Wg,Wu: [d][h] -> [h][d] bf16 ;  Wd: [h][d] -> [d][h] bf16
  transpose_cvt<<<dim3(HID / 64, DIM / 64, NEXP), 256, 0, stream>>>(Wg, wg_t, DIM, HID);
  transpose_cvt<<<dim3(HID / 64, DIM / 64, NEXP), 256, 0, stream>>>(Wu, wu_t, DIM, HID);
  transpose_cvt<<<dim3(DIM / 64, HID / 64, NEXP), 256, 0, stream>>>(Wd, wd_t, HID, DIM);

  // fused gate+up: hact = silu(xe@Wg) * (xe@Wu)   [B reg-staged, decoupled vmcnt]
  gateup_gemm3<<<8 * 22 * 5, 512, 131072, stream>>>(xe, wg_t, wu_t, counts, hact);
  // down + fused gather/scale: y[tok] = (hact @ Wd) * score  [2 blocks/CU]
  down_gemm3<<<8 * 8 * 10, 256, 65536, stream>>>(hact, wd_t, counts, slot_token, scores, y);
}

// Round 4
// 561.692 us; speedup vs baseline: 1.6483x; 1.6483x over previous
//
#include <hip/hip_runtime.h>
#include <cstdint>
#include <cstddef>

#define N_TOK 8192
#define DIM   1024
#define NEXP  8
#define HID   2816
#define CAP   1280   // int(1.25 * 8192 / 8)

typedef __bf16 bf16x8 __attribute__((ext_vector_type(8)));
typedef float  floatx4 __attribute__((ext_vector_type(4)));
typedef unsigned short u16x8 __attribute__((ext_vector_type(8)));

__device__ __forceinline__ unsigned short f2bf(float f) {
  return __builtin_bit_cast(unsigned short, (__bf16)f);
}

// async global->LDS, 16B per lane. LDS dest must be wave-uniform base + lane*16.
__device__ __forceinline__ void async16(void* lds, const void* g) {
  __builtin_amdgcn_global_load_lds(
      (const __attribute__((address_space(1))) void*)g,
      (__attribute__((address_space(3))) void*)lds, 16, 0, 0);
}

__device__ __forceinline__ void fence_barrier() {
  asm volatile("" ::: "memory");
  __builtin_amdgcn_s_barrier();
  asm volatile("" ::: "memory");
}

__device__ __forceinline__ floatx4 mfma16(bf16x8 a, bf16x8 b, floatx4 c) {
  return __builtin_amdgcn_mfma_f32_16x16x32_bf16(a, b, c, 0, 0, 0);
}

// ---------------------------------------------------------------------------
// Routing: FCFS position of each token in its expert queue. One block, 256 thr.
// Hillis-Steele scan over 256 chunk-histograms, static-indexed counters.
// ---------------------------------------------------------------------------
__global__ void route_kernel(const int* __restrict__ idx, int idx_stride,
                             int* __restrict__ slot,
                             int* __restrict__ slot_token,
                             int* __restrict__ counts) {
  __shared__ int hist[256][NEXP];
  const int t = threadIdx.x;
  int loc[NEXP];
#pragma unroll
  for (int e = 0; e < NEXP; e++) loc[e] = 0;
  const int base = t * 32;
  for (int i = 0; i < 32; i++) {
    const int e = idx[(base + i) * idx_stride];
#pragma unroll
    for (int k = 0; k < NEXP; k++) loc[k] += (e == k) ? 1 : 0;
  }
  int v[NEXP];
#pragma unroll
  for (int e = 0; e < NEXP; e++) { v[e] = loc[e]; hist[t][e] = loc[e]; }
  __syncthreads();
  for (int d = 1; d < 256; d <<= 1) {
    int nb[NEXP];
    const bool has = (t >= d);
    if (has) {
#pragma unroll
      for (int e = 0; e < NEXP; e++) nb[e] = hist[t - d][e];
    }
    __syncthreads();
    if (has) {
#pragma unroll
      for (int e = 0; e < NEXP; e++) { v[e] += nb[e]; hist[t][e] = v[e]; }
    }
    __syncthreads();
  }
  if (t < NEXP) {
    const int tot = hist[255][t];
    counts[t] = tot < CAP ? tot : CAP;
  }
  int b2[NEXP];
#pragma unroll
  for (int e = 0; e < NEXP; e++) b2[e] = v[e] - loc[e];  // exclusive base
  for (int i = 0; i < 32; i++) {
    const int n = base + i;
    const int e = idx[n * idx_stride];
    int p = 0;
#pragma unroll
    for (int k = 0; k < NEXP; k++) {
      if (e == k) { p = b2[k]; b2[k] = p + 1; }
    }
    if (p < CAP) {
      const int s = e * CAP + p;
      slot[n] = s;
      slot_token[s] = n;
    } else {
      slot[n] = -1;  // dropped -> passthrough
    }
  }
}

// ---------------------------------------------------------------------------
// Dispatch: kept tokens -> bf16 xe[slot]; dropped tokens -> y = x (fp32).
// ---------------------------------------------------------------------------
__global__ void dispatch_kernel(const float* __restrict__ x,
                                const int* __restrict__ slot,
                                unsigned short* __restrict__ xe,
                                float* __restrict__ y) {
  const int n = blockIdx.x;
  const int t = threadIdx.x;
  const int s = slot[n];
  const float4 v = ((const float4*)(x + (size_t)n * DIM))[t];
  if (s >= 0) {
    ushort4 b;
    b.x = f2bf(v.x); b.y = f2bf(v.y); b.z = f2bf(v.z); b.w = f2bf(v.w);
    ((ushort4*)(xe + (size_t)s * DIM))[t] = b;
  } else {
    ((float4*)(y + (size_t)n * DIM))[t] = v;
  }
}

// ---------------------------------------------------------------------------
// Transpose + fp32->bf16: in [E][R][C] fp32 -> out [E][C][R] bf16.
// ---------------------------------------------------------------------------
__global__ __launch_bounds__(256)
void transpose_cvt(const float* __restrict__ in,
                   unsigned short* __restrict__ out,
                   const int R, const int C) {
  __shared__ float tile[64][65];
  const int e = blockIdx.z;
  const float* ib = in + (size_t)e * R * C;
  unsigned short* ob = out + (size_t)e * R * C;
  const int t = threadIdx.x;
  const int c0 = blockIdx.x * 64, r0 = blockIdx.y * 64;
  const int lr = t >> 4;
  const int lc = (t & 15) * 4;
#pragma unroll
  for (int i = 0; i < 4; i++) {
    const float4 v = *(const float4*)(ib + (size_t)(r0 + lr + i * 16) * C + c0 + lc);
    tile[lr + i * 16][lc + 0] = v.x;
    tile[lr + i * 16][lc + 1] = v.y;
    tile[lr + i * 16][lc + 2] = v.z;
    tile[lr + i * 16][lc + 3] = v.w;
  }
  __syncthreads();
  const int oc = t >> 2;
  const int sub = t & 3;
#pragma unroll
  for (int half = 0; half < 2; half++) {
    const int rch = sub + half * 4;
    u16x8 o;
#pragma unroll
    for (int j = 0; j < 8; j++) o[j] = f2bf(tile[rch * 8 + j][oc]);
    *(u16x8*)(ob + (size_t)(c0 + oc) * R + r0 + rch * 8) = o;
  }
}

// ---------------------------------------------------------------------------
// GEMM kernels: 4-deep LDS pipeline, BK=32, ONE barrier per K-step, fragment
// prefetch (ds_read frags(T+1) issued BEFORE MFMA(T); lgkmcnt(0) after MFMA)
// so the LDS batch hides under the matrix pipe. Counted vmcnt chains: stage
// slot T+3, drain slot T+1 (2-step lead). LDS paired-row layout: 2 M-rows per
// 128B line ([pair][8 x 16B chunks]); chunk swizzle phys = log ^ (pair&7)
// (8-chunk family -> bank-conflict-free b128 reads, as measured rounds 0-2).
// Staging: linear gl_lds dest (t*16), inverse-swizzled per-lane global source.
// ---------------------------------------------------------------------------

// ===================== fused gate+up =====================
// Tile 256M x 64N (x2 matrices), 8 waves (4 wr x 2 wc): per wave 64 rows x
// 32 cols x 2 mats. Slot = A 16K | Bg 4K | Bu 4K = 24 KB; 4 slots = 96 KB.
// 3 gl_lds per wave per step (A x2, B-combined x1). NT = 32.
__global__ __launch_bounds__(512, 2)
void gateup_gemm4(const unsigned short* __restrict__ A,
                  const unsigned short* __restrict__ Bg,
                  const unsigned short* __restrict__ Bu,
                  const int* __restrict__ counts,
                  unsigned short* __restrict__ hact) {
  extern __shared__ __align__(16) char smem[];
  // grid 1760 = 8 xcd * (44 cgl * 5 m); all 5 m-blocks of (n,e) on one XCD.
  const int bid = blockIdx.x;
  const int xcd = bid & 7;
  const int slotb = bid >> 3;      // 0..219
  const int m = slotb % 5;
  const int cgl = slotb / 5;       // 0..43
  const int cg = xcd + 8 * cgl;    // 0..351
  const int n = cg % 44;
  const int e = cg / 44;

  const int cnt = counts[e];
  const int m0 = m * 256;
  if (m0 >= cnt) return;
  const int n0 = n * 64;

  const int t = threadIdx.x;
  const int lane = t & 63;
  const int w = t >> 6;
  const int wr = w >> 1;     // 0..3 : 64-row slice
  const int wc = w & 1;      // 0..1 : 32-col slice per matrix
  const int li = lane & 15;
  const int q = lane >> 4;   // k-granule 0..3 (k = q*8 + j)

  // frag-read offsets (paired-row layout): row r -> pair r>>1, chunk
  // phys = ((r&1)*4 + q) ^ (pair&7); row bases are multiples of 16 so
  // (pair&7) = (li>>1) and phys is constant across mi/ni.
  const int cphys = (((li & 1) * 4 + q) ^ (li >> 1)) * 16;
  const int aoff0 = (wr * 32 + (li >> 1)) * 128 + cphys;              // + mi*1024
  const int boff0 = 16384 + (wc * 16 + (li >> 1)) * 128 + cphys;      // + mat*4096 + ni*1024

  // staging source (inverse swizzle): thread t writes LDS linear t*16 =
  // (pair t>>3, phys chunk t&7); logical chunk = (t&7)^((t>>3)&7);
  // source row = 2*pair + (clog>>2), k-bytes (clog&3)*16.
  const int clog = (t & 7) ^ ((t >> 3) & 7);
  const int kc = (clog & 3) * 8;                 // element offset in k
  const int rloc = 2 * (t >> 3) + (clog >> 2);   // 0..127
  const unsigned short* aSrc  = A + ((size_t)e * CAP + m0 + rloc) * DIM + kc;
  const unsigned short* aSrc2 = aSrc + (size_t)128 * DIM;
  const int rB = n0 + 2 * ((t >> 3) & 31) + (clog >> 2);
  const unsigned short* bSrc =
      ((t < 256) ? Bg : Bu) + ((size_t)e * HID + rB) * DIM + kc;

  floatx4 accg[4][2] = {};
  floatx4 accu[4][2] = {};
  bf16x8 fA[8], fB[8];

  constexpr int NTK = DIM / 32;  // 32

#define GU_STAGE(TN)                                                        \
  {                                                                         \
    char* bb_ = smem + ((TN) & 3) * 24576;                                  \
    const int ko_ = (TN) * 32;                                              \
    async16(bb_ + t * 16, aSrc + ko_);                                      \
    async16(bb_ + 8192 + t * 16, aSrc2 + ko_);                              \
    async16(bb_ + 16384 + t * 16, bSrc + ko_);                              \
  }

#define GU_READF(DST, TN)                                                   \
  {                                                                         \
    const char* sb_ = smem + ((TN) & 3) * 24576;                            \
    DST[0] = *(const bf16x8*)(sb_ + aoff0);                                 \
    DST[1] = *(const bf16x8*)(sb_ + aoff0 + 1024);                          \
    DST[2] = *(const bf16x8*)(sb_ + aoff0 + 2048);                          \
    DST[3] = *(const bf16x8*)(sb_ + aoff0 + 3072);                          \
    DST[4] = *(const bf16x8*)(sb_ + boff0);                                 \
    DST[5] = *(const bf16x8*)(sb_ + boff0 + 1024);                          \
    DST[6] = *(const bf16x8*)(sb_ + boff0 + 4096);                          \
    DST[7] = *(const bf16x8*)(sb_ + boff0 + 5120);                          \
  }

#define GU_MFMA(CUR)                                                        \
  {                                                                         \
    __builtin_amdgcn_s_setprio(1);                                          \
    _Pragma("unroll")                                                       \
    for (int mi = 0; mi < 4; mi++) {                                        \
      accg[mi][0] = mfma16(CUR[mi], CUR[4], accg[mi][0]);                   \
      accg[mi][1] = mfma16(CUR[mi], CUR[5], accg[mi][1]);                   \
      accu[mi][0] = mfma16(CUR[mi], CUR[6], accu[mi][0]);                   \
      accu[mi][1] = mfma16(CUR[mi], CUR[7], accu[mi][1]);                   \
    }                                                                       \
    __builtin_amdgcn_s_setprio(0);                                          \
  }

#define GU_BODY(TN, CUR, NXT)                                               \
  {                                                                         \
    if ((TN) + 3 < NTK) GU_STAGE((TN) + 3);                                 \
    if ((TN) + 1 < NTK) {                                                   \
      if ((TN) + 3 < NTK)      asm volatile("s_waitcnt vmcnt(6)" ::: "memory"); \
      else if ((TN) + 2 < NTK) asm volatile("s_waitcnt vmcnt(3)" ::: "memory"); \
      else                     asm volatile("s_waitcnt vmcnt(0)" ::: "memory"); \
      fence_barrier();                                                      \
      GU_READF(NXT, (TN) + 1);                                              \
      __builtin_amdgcn_sched_barrier(0);                                    \
    }                                                                       \
    GU_MFMA(CUR);                                                           \
    asm volatile("s_waitcnt lgkmcnt(0)" ::: "memory");                      \
    __builtin_amdgcn_sched_barrier(0);                                      \
  }

  // prologue: stage slots 0..2, drain slot 0, read frags(0).
  GU_STAGE(0); GU_STAGE(1); GU_STAGE(2);
  asm volatile("s_waitcnt vmcnt(6)" ::: "memory");
  fence_barrier();
  GU_READF(fA, 0);
  asm volatile("s_waitcnt lgkmcnt(0)" ::: "memory");
  __builtin_amdgcn_sched_barrier(0);

  for (int T = 0; T < NTK; T += 2) {
    GU_BODY(T, fA, fB);
    GU_BODY(T + 1, fB, fA);
  }
#undef GU_BODY
#undef GU_MFMA
#undef GU_READF
#undef GU_STAGE

  // epilogue: hact = silu(g)*u. C/D: col = lane&15, row = (lane>>4)*4 + reg.
  unsigned short* ob = hact + (size_t)e * CAP * HID;
#pragma unroll
  for (int mi = 0; mi < 4; mi++)
#pragma unroll
    for (int r = 0; r < 4; r++) {
      const int row = m0 + wr * 64 + mi * 16 + q * 4 + r;
      const size_t rb = (size_t)row * HID;
#pragma unroll
      for (int ni = 0; ni < 2; ni++) {
        const int col = n0 + wc * 32 + ni * 16 + li;
        const float g = accg[mi][ni][r];
        const float u = accu[mi][ni][r];
        ob[rb + col] = f2bf(g / (1.0f + __expf(-g)) * u);
      }
    }
}

// ===================== down + gather/scale =====================
// Tile 128M x 128N, 4 waves (2x2): per wave 64x64. Slot = A 8K | B 8K = 16 KB;
// 4 slots = 64 KB -> 2 blocks/CU (512 active blocks all co-resident).
// 4 gl_lds per wave per step. NT = 88.
__global__ __launch_bounds__(256, 2)
void down_gemm4(const unsigned short* __restrict__ Ah,
                const unsigned short* __restrict__ Bt,
                const int* __restrict__ counts,
                const int* __restrict__ slot_token,
                const float* __restrict__ scores,
                float* __restrict__ y) {
  extern __shared__ __align__(16) char smem[];
  // grid 640 = 8 xcd * (8 cgl * 10 m)
  const int bid = blockIdx.x;
  const int xcd = bid & 7;
  const int slotb = bid >> 3;      // 0..79
  const int m = slotb % 10;
  const int cgl = slotb / 10;      // 0..7
  const int cg = xcd + 8 * cgl;    // 0..63
  const int n = cg % 8;
  const int e = cg / 8;

  const int cnt = counts[e];
  const int m0 = m * 128;
  if (m0 >= cnt) return;
  const int n0 = n * 128;

  const int t = threadIdx.x;
  const int lane = t & 63;
  const int w = t >> 6;
  const int wr = w >> 1;     // 0..1
  const int wc = w & 1;      // 0..1
  const int li = lane & 15;
  const int q = lane >> 4;

  const int cphys = (((li & 1) * 4 + q) ^ (li >> 1)) * 16;
  const int aoff0 = (wr * 32 + (li >> 1)) * 128 + cphys;          // + mi*1024
  const int boff0 = 8192 + (wc * 32 + (li >> 1)) * 128 + cphys;   // + ni*1024

  const int clog = (t & 7) ^ ((t >> 3) & 7);
  const int kc = (clog & 3) * 8;
  const int rloc = 2 * (t >> 3) + (clog >> 2);   // 0..63
  const unsigned short* aSrc  = Ah + ((size_t)e * CAP + m0 + rloc) * HID + kc;
  const unsigned short* aSrc2 = aSrc + (size_t)64 * HID;
  const unsigned short* bSrc  = Bt + ((size_t)e * DIM + n0 + rloc) * HID + kc;
  const unsigned short* bSrc2 = bSrc + (size_t)64 * HID;

  floatx4 acc[4][4] = {};
  bf16x8 fA[8], fB[8];

  constexpr int NTK = HID / 32;  // 88

#define DN_STAGE(TN)                                                        \
  {                                                                         \
    char* bb_ = smem + ((TN) & 3) * 16384;                                  \
    const int ko_ = (TN) * 32;                                              \
    async16(bb_ + t * 16, aSrc + ko_);                                      \
    async16(bb_ + 4096 + t * 16, aSrc2 + ko_);                              \
    async16(bb_ + 8192 + t * 16, bSrc + ko_);                               \
    async16(bb_ + 12288 + t * 16, bSrc2 + ko_);                             \
  }

#define DN_READF(DST, TN)                                                   \
  {                                                                         \
    const char* sb_ = smem + ((TN) & 3) * 16384;                            \
    DST[0] = *(const bf16x8*)(sb_ + aoff0);                                 \
    DST[1] = *(const bf16x8*)(sb_ + aoff0 + 1024);                          \
    DST[2] = *(const bf16x8*)(sb_ + aoff0 + 2048);                          \
    DST[3] = *(const bf16x8*)(sb_ + aoff0 + 3072);                          \
    DST[4] = *(const bf16x8*)(sb_ + boff0);                                 \
    DST[5] = *(const bf16x8*)(sb_ + boff0 + 1024);                          \
    DST[6] = *(const bf16x8*)(sb_ + boff0 + 2048);                          \
    DST[7] = *(const bf16x8*)(sb_ + boff0 + 3072);                          \
  }

#define DN_MFMA(CUR)                                                        \
  {                                                                         \
    __builtin_amdgcn_s_setprio(1);                                          \
    _Pragma("unroll")                                                       \
    for (int mi = 0; mi < 4; mi++) {                                        \
      _Pragma("unroll")                                                     \
      for (int ni = 0; ni < 4; ni++)                                        \
        acc[mi][ni] = mfma16(CUR[mi], CUR[4 + ni], acc[mi][ni]);            \
    }                                                                       \
    __builtin_amdgcn_s_setprio(0);                                          \
  }

#define DN_BODY(TN, CUR, NXT)                                               \
  {                                                                         \
    if ((TN) + 3 < NTK) DN_STAGE((TN) + 3);                                 \
    if ((TN) + 1 < NTK) {                                                   \
      if ((TN) + 3 < NTK)      asm volatile("s_waitcnt vmcnt(8)" ::: "memory"); \
      else if ((TN) + 2 < NTK) asm volatile("s_waitcnt vmcnt(4)" ::: "memory"); \
      else                     asm volatile("s_waitcnt vmcnt(0)" ::: "memory"); \
      fence_barrier();                                                      \
      DN_READF(NXT, (TN) + 1);                                              \
      __builtin_amdgcn_sched_barrier(0);                                    \
    }                                                                       \
    DN_MFMA(CUR);                                                           \
    asm volatile("s_waitcnt lgkmcnt(0)" ::: "memory");                      \
    __builtin_amdgcn_sched_barrier(0);                                      \
  }

  DN_STAGE(0); DN_STAGE(1); DN_STAGE(2);
  asm volatile("s_waitcnt vmcnt(8)" ::: "memory");
  fence_barrier();
  DN_READF(fA, 0);
  asm volatile("s_waitcnt lgkmcnt(0)" ::: "memory");
  __builtin_amdgcn_sched_barrier(0);

  for (int T = 0; T < NTK; T += 2) {
    DN_BODY(T, fA, fB);
    DN_BODY(T + 1, fB, fA);
  }
#undef DN_BODY
#undef DN_MFMA
#undef DN_READF
#undef DN_STAGE

  // epilogue: y[tok] = acc * score (row < cnt only)
#pragma unroll
  for (int mi = 0; mi < 4; mi++)
#pragma unroll
    for (int r = 0; r < 4; r++) {
      const int row = m0 + wr * 64 + mi * 16 + q * 4 + r;
      if (row < cnt) {
        const int tok = slot_token[e * CAP + row];
        const float s = scores[tok];
        float* yr = y + (size_t)tok * DIM;
#pragma unroll
        for (int ni = 0; ni < 4; ni++) {
          const int col = n0 + wc * 64 + ni * 16 + li;
          yr[col] = acc[mi][ni][r] * s;
        }
      }
    }
}

extern "C" void kernel_launch(void* const* d_in, const int* in_sizes, int n_in,
                              void* d_out, int out_size, void* d_ws, size_t ws_size,
                              hipStream_t stream) {
  const float* x      = (const float*)d_in[0];
  const int*   idx    = (const int*)d_in[1];
  const float* scores = (const float*)d_in[2];
  const float* Wg     = (const float*)d_in[3];
  const float* Wu     = (const float*)d_in[4];
  const float* Wd     = (const float*)d_in[5];
  float* y = (float*)d_out;

  const int idx_stride = (in_sizes[1] == 2 * N_TOK) ? 2 : 1;

  char* ws = (char*)d_ws;
  size_t off = 0;
  auto alloc = [&](size_t b) -> char* {
    char* p = ws + off;
    off += (b + 255) & ~(size_t)255;
    return p;
  };
  int* counts            = (int*)alloc(NEXP * 4);
  int* slot              = (int*)alloc((size_t)N_TOK * 4);
  int* slot_token        = (int*)alloc((size_t)NEXP * CAP * 4);
  unsigned short* xe     = (unsigned short*)alloc((size_t)NEXP * CAP * DIM * 2);
  unsigned short* hact   = (unsigned short*)alloc((size_t)NEXP * CAP * HID * 2);
  unsigned short* wg_t   = (unsigned short*)alloc((size_t)NEXP * DIM * HID * 2);
  unsigned short* wu_t   = (unsigned short*)alloc((size_t)NEXP * DIM * HID * 2);
  unsigned short* wd_t   = (unsigned short*)alloc((size_t)NEXP * DIM * HID * 2);
  (void)ws_size; (void)n_in; (void)out_size;

  static bool s_attr_done = false;
  if (!s_attr_done) {
    hipFuncSetAttribute((const void*)gateup_gemm4,
                        hipFuncAttributeMaxDynamicSharedMemorySize, 98304);
    hipFuncSetAttribute((const void*)down_gemm4,
                        hipFuncAttributeMaxDynamicSharedMemorySize, 65536);
    s_attr_done = true;
  }

  route_kernel<<<1, 256, 0, stream>>>(idx, idx_stride, slot, slot_token, counts);
  dispatch_kernel<<<N_TOK, 256, 0, stream>>>(x, slot, xe, y);

  // Wg,Wu: [d][h] -> [h][d] bf16 ;  Wd: [h][d] -> [d][h] bf16
  transpose_cvt<<<dim3(HID / 64, DIM / 64, NEXP), 256, 0, stream>>>(Wg, wg_t, DIM, HID);
  transpose_cvt<<<dim3(HID / 64, DIM / 64, NEXP), 256, 0, stream>>>(Wu, wu_t, DIM, HID);
  transpose_cvt<<<dim3(DIM / 64, HID / 64, NEXP), 256, 0, stream>>>(Wd, wd_t, HID, DIM);

  // fused gate+up: hact = silu(xe@Wg) * (xe@Wu)  [4-deep pipe, 1 barrier/step]
  gateup_gemm4<<<8 * 44 * 5, 512, 98304, stream>>>(xe, wg_t, wu_t, counts, hact);
  // down + fused gather/scale: y[tok] = (hact @ Wd) * score  [2 blocks/CU]
  down_gemm4<<<8 * 8 * 10, 256, 65536, stream>>>(hact, wd_t, counts, slot_token, scores, y);
}

// Round 6
// 541.088 us; speedup vs baseline: 1.7111x; 1.0381x over previous
//
#include <hip/hip_runtime.h>
#include <cstdint>
#include <cstddef>

#define N_TOK 8192
#define DIM   1024
#define NEXP  8
#define HID   2816
#define CAP   1280   // int(1.25 * 8192 / 8)

typedef __bf16 bf16x8 __attribute__((ext_vector_type(8)));
typedef float  floatx4 __attribute__((ext_vector_type(4)));
typedef unsigned short u16x8 __attribute__((ext_vector_type(8)));

__device__ __forceinline__ unsigned short f2bf(float f) {
  return __builtin_bit_cast(unsigned short, (__bf16)f);
}

// async global->LDS, 16B per lane. LDS dest must be wave-uniform base + lane*16.
__device__ __forceinline__ void async16(void* lds, const void* g) {
  __builtin_amdgcn_global_load_lds(
      (const __attribute__((address_space(1))) void*)g,
      (__attribute__((address_space(3))) void*)lds, 16, 0, 0);
}

__device__ __forceinline__ void fence_barrier() {
  asm volatile("" ::: "memory");
  __builtin_amdgcn_s_barrier();
  asm volatile("" ::: "memory");
}

__device__ __forceinline__ floatx4 mfma16(bf16x8 a, bf16x8 b, floatx4 c) {
  return __builtin_amdgcn_mfma_f32_16x16x32_bf16(a, b, c, 0, 0, 0);
}

// ---------------------------------------------------------------------------
// Routing: FCFS position of each token in its expert queue. One block, 256 thr.
// ---------------------------------------------------------------------------
__global__ void route_kernel(const int* __restrict__ idx, int idx_stride,
                             int* __restrict__ slot,
                             int* __restrict__ slot_token,
                             int* __restrict__ counts) {
  __shared__ int hist[256][NEXP];
  const int t = threadIdx.x;
  int loc[NEXP];
#pragma unroll
  for (int e = 0; e < NEXP; e++) loc[e] = 0;
  const int base = t * 32;
  for (int i = 0; i < 32; i++) {
    const int e = idx[(base + i) * idx_stride];
#pragma unroll
    for (int k = 0; k < NEXP; k++) loc[k] += (e == k) ? 1 : 0;
  }
  int v[NEXP];
#pragma unroll
  for (int e = 0; e < NEXP; e++) { v[e] = loc[e]; hist[t][e] = loc[e]; }
  __syncthreads();
  for (int d = 1; d < 256; d <<= 1) {
    int nb[NEXP];
    const bool has = (t >= d);
    if (has) {
#pragma unroll
      for (int e = 0; e < NEXP; e++) nb[e] = hist[t - d][e];
    }
    __syncthreads();
    if (has) {
#pragma unroll
      for (int e = 0; e < NEXP; e++) { v[e] += nb[e]; hist[t][e] = v[e]; }
    }
    __syncthreads();
  }
  if (t < NEXP) {
    const int tot = hist[255][t];
    counts[t] = tot < CAP ? tot : CAP;
  }
  int b2[NEXP];
#pragma unroll
  for (int e = 0; e < NEXP; e++) b2[e] = v[e] - loc[e];  // exclusive base
  for (int i = 0; i < 32; i++) {
    const int n = base + i;
    const int e = idx[n * idx_stride];
    int p = 0;
#pragma unroll
    for (int k = 0; k < NEXP; k++) {
      if (e == k) { p = b2[k]; b2[k] = p + 1; }
    }
    if (p < CAP) {
      const int s = e * CAP + p;
      slot[n] = s;
      slot_token[s] = n;
    } else {
      slot[n] = -1;  // dropped -> passthrough
    }
  }
}

// ---------------------------------------------------------------------------
// Dispatch: kept tokens -> bf16 xe[slot]; dropped tokens -> y = x (fp32).
// ---------------------------------------------------------------------------
__global__ void dispatch_kernel(const float* __restrict__ x,
                                const int* __restrict__ slot,
                                unsigned short* __restrict__ xe,
                                float* __restrict__ y) {
  const int n = blockIdx.x;
  const int t = threadIdx.x;
  const int s = slot[n];
  const float4 v = ((const float4*)(x + (size_t)n * DIM))[t];
  if (s >= 0) {
    ushort4 b;
    b.x = f2bf(v.x); b.y = f2bf(v.y); b.z = f2bf(v.z); b.w = f2bf(v.w);
    ((ushort4*)(xe + (size_t)s * DIM))[t] = b;
  } else {
    ((float4*)(y + (size_t)n * DIM))[t] = v;
  }
}

// ---------------------------------------------------------------------------
// Transpose + fp32->bf16: in [E][R][C] fp32 -> out [E][C][R] bf16.
// ---------------------------------------------------------------------------
__global__ __launch_bounds__(256)
void transpose_cvt(const float* __restrict__ in,
                   unsigned short* __restrict__ out,
                   const int R, const int C) {
  __shared__ float tile[64][65];
  const int e = blockIdx.z;
  const float* ib = in + (size_t)e * R * C;
  unsigned short* ob = out + (size_t)e * R * C;
  const int t = threadIdx.x;
  const int c0 = blockIdx.x * 64, r0 = blockIdx.y * 64;
  const int lr = t >> 4;
  const int lc = (t & 15) * 4;
#pragma unroll
  for (int i = 0; i < 4; i++) {
    const float4 v = *(const float4*)(ib + (size_t)(r0 + lr + i * 16) * C + c0 + lc);
    tile[lr + i * 16][lc + 0] = v.x;
    tile[lr + i * 16][lc + 1] = v.y;
    tile[lr + i * 16][lc + 2] = v.z;
    tile[lr + i * 16][lc + 3] = v.w;
  }
  __syncthreads();
  const int oc = t >> 2;
  const int sub = t & 3;
#pragma unroll
  for (int half = 0; half < 2; half++) {
    const int rch = sub + half * 4;
    u16x8 o;
#pragma unroll
    for (int j = 0; j < 8; j++) o[j] = f2bf(tile[rch * 8 + j][oc]);
    *(u16x8*)(ob + (size_t)(c0 + oc) * R + r0 + rch * 8) = o;
  }
}

// ---------------------------------------------------------------------------
// GEMMs with EXPERT->XCD affinity (NEXP == 8 XCDs): e = bid & 7, so ALL blocks
// reading one expert's activation panel run on one XCD -> A re-reads served by
// that XCD's L2 (panel is 2.6 MB < 4 MB) instead of the ~5 TB/s LLC path that
// was the measured invariant limiter of rounds 0-4. B panels stream from HBM
// once and are shared via L2 by co-resident/consecutive m-blocks.
//
// Pipeline (both GEMMs): 3 LDS slots, BK=32, 2-step prefetch lead, ONE barrier
// per K-step, uniform counted vmcnt(S):
//   [vmcnt(S) -> barrier -> ds_read frags(T) ; stage(T+2) -> lgkmcnt(0) ->
//    sched_barrier -> MFMA(T)]
// LDS paired-row layout: 2 rows per 128B line, chunk swizzle phys=log^(pair&7)
// (bank-conflict-free b128, verified rounds 0-4). Staging: linear gl_lds dest,
// inverse-swizzled per-lane global source.
// ---------------------------------------------------------------------------

// ===================== fused gate+up =====================
// Tile 256M x 128N x2 mats, 8 waves (2 wr x 4 wc): per wave 128x32 per mat.
// Slot = A 16K | Bg 8K | Bu 8K = 32 KB; 3 slots = 96 KB. S=4 gl_lds/thread.
// Grid 880 = 8 xcd(=expert) * (22 n * 5 m), m inner.
__global__ __launch_bounds__(512, 2)
void gateup_gemm5(const unsigned short* __restrict__ A,
                  const unsigned short* __restrict__ Bg,
                  const unsigned short* __restrict__ Bu,
                  const int* __restrict__ counts,
                  unsigned short* __restrict__ hact) {
  extern __shared__ __align__(16) char smem[];
  const int bid = blockIdx.x;
  const int e = bid & 7;           // expert == XCD
  const int local = bid >> 3;      // 0..109
  const int n = local / 5;         // 0..21
  const int m = local % 5;

  const int cnt = counts[e];
  const int m0 = m * 256;
  if (m0 >= cnt) return;
  const int n0 = n * 128;

  const int t = threadIdx.x;
  const int lane = t & 63;
  const int w = t >> 6;
  const int wr = w >> 2;     // 0..1 : 128-row slice
  const int wc = w & 3;      // 0..3 : 32-col slice per matrix
  const int li = lane & 15;
  const int q = lane >> 4;

  // frag-read offsets (paired-row + chunk swizzle)
  const int cphys = (((li & 1) * 4 + q) ^ (li >> 1)) * 16;
  const int aoff0 = wr * 8192 + (li >> 1) * 128 + cphys;             // + mi*1024
  const int bgoff = 16384 + wc * 2048 + (li >> 1) * 128 + cphys;     // + ni*1024
  const int buoff = bgoff + 8192;

  // staging source (inverse swizzle), 8KB regions of 512 thr x 16B
  const int clog = (t & 7) ^ ((t >> 3) & 7);
  const int kc = (clog & 3) * 8;
  const int rloc = 2 * (t >> 3) + (clog >> 2);   // 0..127
  const unsigned short* aS0 = A  + ((size_t)e * CAP + m0 + rloc) * DIM + kc;
  const unsigned short* aS1 = aS0 + (size_t)128 * DIM;
  const unsigned short* bgS = Bg + ((size_t)e * HID + n0 + rloc) * DIM + kc;
  const unsigned short* buS = Bu + ((size_t)e * HID + n0 + rloc) * DIM + kc;

  floatx4 accg[8][2] = {};
  floatx4 accu[8][2] = {};

  constexpr int NTK = DIM / 32;  // 32

#define GU_STAGE(TN)                                                        \
  {                                                                         \
    char* bb_ = smem + ((TN) % 3) * 32768;                                  \
    const int ko_ = (TN) * 32;                                              \
    async16(bb_ + t * 16, aS0 + ko_);                                       \
    async16(bb_ + 8192 + t * 16, aS1 + ko_);                                \
    async16(bb_ + 16384 + t * 16, bgS + ko_);                               \
    async16(bb_ + 24576 + t * 16, buS + ko_);                               \
  }

  GU_STAGE(0);
  GU_STAGE(1);

  for (int T = 0; T < NTK; T++) {
    if (T + 1 < NTK) asm volatile("s_waitcnt vmcnt(4)" ::: "memory");
    else             asm volatile("s_waitcnt vmcnt(0)" ::: "memory");
    fence_barrier();
    const char* sb = smem + (T % 3) * 32768;
    bf16x8 fa[8], fg[2], fu[2];
#pragma unroll
    for (int mi = 0; mi < 8; mi++)
      fa[mi] = *(const bf16x8*)(sb + aoff0 + mi * 1024);
#pragma unroll
    for (int ni = 0; ni < 2; ni++) {
      fg[ni] = *(const bf16x8*)(sb + bgoff + ni * 1024);
      fu[ni] = *(const bf16x8*)(sb + buoff + ni * 1024);
    }
    if (T + 2 < NTK) GU_STAGE(T + 2);
    asm volatile("s_waitcnt lgkmcnt(0)" ::: "memory");
    __builtin_amdgcn_sched_barrier(0);
    __builtin_amdgcn_s_setprio(1);
#pragma unroll
    for (int mi = 0; mi < 8; mi++) {
      accg[mi][0] = mfma16(fa[mi], fg[0], accg[mi][0]);
      accg[mi][1] = mfma16(fa[mi], fg[1], accg[mi][1]);
      accu[mi][0] = mfma16(fa[mi], fu[0], accu[mi][0]);
      accu[mi][1] = mfma16(fa[mi], fu[1], accu[mi][1]);
    }
    __builtin_amdgcn_s_setprio(0);
  }
#undef GU_STAGE

  // epilogue: hact = silu(g)*u. C/D: col = lane&15, row = (lane>>4)*4 + reg.
  unsigned short* ob = hact + (size_t)e * CAP * HID;
#pragma unroll
  for (int mi = 0; mi < 8; mi++)
#pragma unroll
    for (int r = 0; r < 4; r++) {
      const int row = m0 + wr * 128 + mi * 16 + q * 4 + r;
      const size_t rb = (size_t)row * HID;
#pragma unroll
      for (int ni = 0; ni < 2; ni++) {
        const int col = n0 + wc * 32 + ni * 16 + li;
        const float g = accg[mi][ni][r];
        const float u = accu[mi][ni][r];
        ob[rb + col] = f2bf(g / (1.0f + __expf(-g)) * u);
      }
    }
}

// ===================== down + gather/scale =====================
// Tile 128M x 128N, 4 waves (2x2): per wave 64x64. Slot = A 8K | B 8K = 16 KB;
// 3 slots = 48 KB -> 3 blocks/CU; 80 blocks/XCD all co-resident (one round).
// S=4 gl_lds/thread (4KB regions of 256 thr x 16B). Grid 640 = 8 * (8 n * 10 m).
__global__ __launch_bounds__(256, 3)
void down_gemm5(const unsigned short* __restrict__ Ah,
                const unsigned short* __restrict__ Bt,
                const int* __restrict__ counts,
                const int* __restrict__ slot_token,
                const float* __restrict__ scores,
                float* __restrict__ y) {
  extern __shared__ __align__(16) char smem[];
  const int bid = blockIdx.x;
  const int e = bid & 7;           // expert == XCD
  const int local = bid >> 3;      // 0..79
  const int n = local / 10;        // 0..7
  const int m = local % 10;

  const int cnt = counts[e];
  const int m0 = m * 128;
  if (m0 >= cnt) return;
  const int n0 = n * 128;

  const int t = threadIdx.x;
  const int lane = t & 63;
  const int w = t >> 6;
  const int wr = w >> 1;     // 0..1
  const int wc = w & 1;      // 0..1
  const int li = lane & 15;
  const int q = lane >> 4;

  const int cphys = (((li & 1) * 4 + q) ^ (li >> 1)) * 16;
  const int aoff0 = wr * 4096 + (li >> 1) * 128 + cphys;          // + mi*1024
  const int boff0 = 8192 + wc * 4096 + (li >> 1) * 128 + cphys;   // + ni*1024

  // staging: 4KB regions of 256 thr x 16B; rows 0..63 per region
  const int clog = (t & 7) ^ ((t >> 3) & 7);
  const int kc = (clog & 3) * 8;
  const int rloc = 2 * (t >> 3) + (clog >> 2);   // 0..63
  const unsigned short* aS0 = Ah + ((size_t)e * CAP + m0 + rloc) * HID + kc;
  const unsigned short* aS1 = aS0 + (size_t)64 * HID;
  const unsigned short* bS0 = Bt + ((size_t)e * DIM + n0 + rloc) * HID + kc;
  const unsigned short* bS1 = bS0 + (size_t)64 * HID;

  floatx4 acc[4][4] = {};

  constexpr int NTK = HID / 32;  // 88

#define DN_STAGE(TN)                                                        \
  {                                                                         \
    char* bb_ = smem + ((TN) % 3) * 16384;                                  \
    const int ko_ = (TN) * 32;                                              \
    async16(bb_ + t * 16, aS0 + ko_);                                       \
    async16(bb_ + 4096 + t * 16, aS1 + ko_);                                \
    async16(bb_ + 8192 + t * 16, bS0 + ko_);                                \
    async16(bb_ + 12288 + t * 16, bS1 + ko_);                               \
  }

  DN_STAGE(0);
  DN_STAGE(1);

  for (int T = 0; T < NTK; T++) {
    if (T + 1 < NTK) asm volatile("s_waitcnt vmcnt(4)" ::: "memory");
    else             asm volatile("s_waitcnt vmcnt(0)" ::: "memory");
    fence_barrier();
    const char* sb = smem + (T % 3) * 16384;
    bf16x8 fa[4], fb[4];
#pragma unroll
    for (int mi = 0; mi < 4; mi++)
      fa[mi] = *(const bf16x8*)(sb + aoff0 + mi * 1024);
#pragma unroll
    for (int ni = 0; ni < 4; ni++)
      fb[ni] = *(const bf16x8*)(sb + boff0 + ni * 1024);
    if (T + 2 < NTK) DN_STAGE(T + 2);
    asm volatile("s_waitcnt lgkmcnt(0)" ::: "memory");
    __builtin_amdgcn_sched_barrier(0);
    __builtin_amdgcn_s_setprio(1);
#pragma unroll
    for (int mi = 0; mi < 4; mi++)
#pragma unroll
      for (int ni = 0; ni < 4; ni++)
        acc[mi][ni] = mfma16(fa[mi], fb[ni], acc[mi][ni]);
    __builtin_amdgcn_s_setprio(0);
  }
#undef DN_STAGE

  // epilogue: y[tok] = acc * score (row < cnt only)
#pragma unroll
  for (int mi = 0; mi < 4; mi++)
#pragma unroll
    for (int r = 0; r < 4; r++) {
      const int row = m0 + wr * 64 + mi * 16 + q * 4 + r;
      if (row < cnt) {
        const int tok = slot_token[e * CAP + row];
        const float s = scores[tok];
        float* yr = y + (size_t)tok * DIM;
#pragma unroll
        for (int ni = 0; ni < 4; ni++) {
          const int col = n0 + wc * 64 + ni * 16 + li;
          yr[col] = acc[mi][ni][r] * s;
        }
      }
    }
}

extern "C" void kernel_launch(void* const* d_in, const int* in_sizes, int n_in,
                              void* d_out, int out_size, void* d_ws, size_t ws_size,
                              hipStream_t stream) {
  const float* x      = (const float*)d_in[0];
  const int*   idx    = (const int*)d_in[1];
  const float* scores = (const float*)d_in[2];
  const float* Wg     = (const float*)d_in[3];
  const float* Wu     = (const float*)d_in[4];
  const float* Wd     = (const float*)d_in[5];
  float* y = (float*)d_out;

  const int idx_stride = (in_sizes[1] == 2 * N_TOK) ? 2 : 1;

  char* ws = (char*)d_ws;
  size_t off = 0;
  auto alloc = [&](size_t b) -> char* {
    char* p = ws + off;
    off += (b + 255) & ~(size_t)255;
    return p;
  };
  int* counts            = (int*)alloc(NEXP * 4);
  int* slot              = (int*)alloc((size_t)N_TOK * 4);
  int* slot_token        = (int*)alloc((size_t)NEXP * CAP * 4);
  unsigned short* xe     = (unsigned short*)alloc((size_t)NEXP * CAP * DIM * 2);
  unsigned short* hact   = (unsigned short*)alloc((size_t)NEXP * CAP * HID * 2);
  unsigned short* wg_t   = (unsigned short*)alloc((size_t)NEXP * DIM * HID * 2);
  unsigned short* wu_t   = (unsigned short*)alloc((size_t)NEXP * DIM * HID * 2);
  unsigned short* wd_t   = (unsigned short*)alloc((size_t)NEXP * DIM * HID * 2);
  (void)ws_size; (void)n_in; (void)out_size;

  static bool s_attr_done = false;
  if (!s_attr_done) {
    hipFuncSetAttribute((const void*)gateup_gemm5,
                        hipFuncAttributeMaxDynamicSharedMemorySize, 98304);
    hipFuncSetAttribute((const void*)down_gemm5,
                        hipFuncAttributeMaxDynamicSharedMemorySize, 49152);
    s_attr_done = true;
  }

  route_kernel<<<1, 256, 0, stream>>>(idx, idx_stride, slot, slot_token, counts);
  dispatch_kernel<<<N_TOK, 256, 0, stream>>>(x, slot, xe, y);

  // Wg,Wu: [d][h] -> [h][d] bf16 ;  Wd: [h][d] -> [d][h] bf16
  transpose_cvt<<<dim3(HID / 64, DIM / 64, NEXP), 256, 0, stream>>>(Wg, wg_t, DIM, HID);
  transpose_cvt<<<dim3(HID / 64, DIM / 64, NEXP), 256, 0, stream>>>(Wu, wu_t, DIM, HID);
  transpose_cvt<<<dim3(DIM / 64, HID / 64, NEXP), 256, 0, stream>>>(Wd, wd_t, HID, DIM);

  // fused gate+up: hact = silu(xe@Wg) * (xe@Wu)  [expert->XCD, A in L2]
  gateup_gemm5<<<8 * 22 * 5, 512, 98304, stream>>>(xe, wg_t, wu_t, counts, hact);
  // down + fused gather/scale: y[tok] = (hact @ Wd) * score  [3 blocks/CU]
  down_gemm5<<<8 * 8 * 10, 256, 49152, stream>>>(hact, wd_t, counts, slot_token, scores, y);
}